// Round 1
// baseline (1733.230 us; speedup 1.0000x reference)
//
#include <hip/hip_runtime.h>
#include <stdint.h>

#define TOKENS 4096
#define DMODEL 4096
#define FC1N   16384
#define FC2N   4096

typedef __attribute__((ext_vector_type(8))) __bf16 bf16x8;
typedef __attribute__((ext_vector_type(4))) float f32x4;

__device__ __forceinline__ unsigned short f2bf(float f) {
  unsigned u = __float_as_uint(f);
  u += 0x7fffu + ((u >> 16) & 1u);          // RNE
  return (unsigned short)(u >> 16);
}

__device__ __forceinline__ float gelu_tanh(float x) {
  float y = 0.7978845608028654f * (x + 0.044715f * x * x * x);
  float e = __expf(2.0f * y);               // tanh(y) = 1 - 2/(e^(2y)+1)
  float t = 1.0f - 2.0f / (e + 1.0f);
  return 0.5f * x * (1.0f + t);
}

// ---------------- LayerNorm: fp32 [T][D] -> bf16 [T][D] -----------------
__global__ __launch_bounds__(256) void ln_kernel(const float* __restrict__ x,
                                                 const float* __restrict__ gamma,
                                                 const float* __restrict__ beta,
                                                 unsigned short* __restrict__ out) {
  const int row = blockIdx.x;
  const int tid = threadIdx.x;
  const float* xr = x + (size_t)row * DMODEL;
  float4 v[4];
  float s = 0.f, s2 = 0.f;
#pragma unroll
  for (int i = 0; i < 4; ++i) {
    v[i] = ((const float4*)xr)[tid + i * 256];
    s  += v[i].x + v[i].y + v[i].z + v[i].w;
    s2 += v[i].x * v[i].x + v[i].y * v[i].y + v[i].z * v[i].z + v[i].w * v[i].w;
  }
#pragma unroll
  for (int o = 32; o > 0; o >>= 1) {
    s  += __shfl_xor(s, o, 64);
    s2 += __shfl_xor(s2, o, 64);
  }
  __shared__ float red[2][4];
  const int wid = tid >> 6, lane = tid & 63;
  if (lane == 0) { red[0][wid] = s; red[1][wid] = s2; }
  __syncthreads();
  s  = red[0][0] + red[0][1] + red[0][2] + red[0][3];
  s2 = red[1][0] + red[1][1] + red[1][2] + red[1][3];
  const float mu = s * (1.f / DMODEL);
  const float var = s2 * (1.f / DMODEL) - mu * mu;
  const float rs = rsqrtf(var + 1e-3f);
  unsigned short* orow = out + (size_t)row * DMODEL;
#pragma unroll
  for (int i = 0; i < 4; ++i) {
    const int c4 = tid + i * 256;
    float4 g = ((const float4*)gamma)[c4];
    float4 b = ((const float4*)beta)[c4];
    ushort4 o;
    o.x = f2bf((v[i].x - mu) * rs * g.x + b.x);
    o.y = f2bf((v[i].y - mu) * rs * g.y + b.y);
    o.z = f2bf((v[i].z - mu) * rs * g.z + b.z);
    o.w = f2bf((v[i].w - mu) * rs * g.w + b.w);
    ((ushort4*)orow)[c4] = o;
  }
}

// --------- transpose+convert: W fp32 [K][N] -> Wt bf16 [N][K] -----------
__global__ __launch_bounds__(256) void transpose_bf16(const float* __restrict__ W,
                                                      unsigned short* __restrict__ Wt,
                                                      int K, int N) {
  __shared__ float t[32][33];
  const int x = threadIdx.x & 31, y = threadIdx.x >> 5;
  const int n0 = blockIdx.x << 5, k0 = blockIdx.y << 5;
#pragma unroll
  for (int i = 0; i < 4; ++i)
    t[y + i * 8][x] = W[(size_t)(k0 + y + i * 8) * N + n0 + x];
  __syncthreads();
#pragma unroll
  for (int i = 0; i < 4; ++i)
    Wt[(size_t)(n0 + y + i * 8) * K + k0 + x] = f2bf(t[x][y + i * 8]);
}

// ---------------- GEMM: C = A[M][K](bf16) * Bt[N][K](bf16)^T -------------
// 128x128 tile, BK=64, 256 threads (4 waves, 2x2), 16x16x32 MFMA.
// LDS tiles [128 rows][64 k] bf16, XOR-swizzled: byte ^= (row&7)<<4.
// Staged via global_load_lds (linear dest, inverse-swizzled global source).
template <bool GELU>
__global__ __launch_bounds__(256) void gemm_bt(const unsigned short* __restrict__ A,
                                               const unsigned short* __restrict__ Bt,
                                               const float* __restrict__ bias,
                                               void* __restrict__ Cout,
                                               int M, int N, int K) {
  __shared__ char smem[32768] __attribute__((aligned(128)));
  const int tid = threadIdx.x;
  const int lane = tid & 63, wid = tid >> 6;

  // XCD-bijective swizzle (nwg % 8 == 0 for both launches)
  const int nwg = gridDim.x;
  const int bid = blockIdx.x;
  const int cpx = nwg >> 3;
  const int wg = (bid & 7) * cpx + (bid >> 3);
  const int nbx = N >> 7;
  const int bx = wg % nbx, by = wg / nbx;
  const int m0 = by << 7, n0 = bx << 7;
  const int wr = wid >> 1, wc = wid & 1;

  const int lane15 = lane & 15, laneHi = lane >> 4;
  const int rswz = (lane15 & 7) << 4;  // read-side XOR (row&7)<<4
  const int aRow = (wr << 6) + lane15;
  const int bRow = (wc << 6) + lane15;

  f32x4 acc[4][4];
#pragma unroll
  for (int m = 0; m < 4; ++m)
#pragma unroll
    for (int n = 0; n < 4; ++n) acc[m][n] = f32x4{0.f, 0.f, 0.f, 0.f};

  const char* ldsA = smem;
  const char* ldsB = smem + 16384;

  for (int k0 = 0; k0 < K; k0 += 64) {
    // stage A and B tiles: 16 chunks of 1KB each; wave w owns chunks w*4..w*4+3
#pragma unroll
    for (int i = 0; i < 4; ++i) {
      const int c = (wid << 2) + i;
      const int o = (c << 10) + (lane << 4);       // linear LDS byte offset
      const int row = o >> 7;                      // tile row (128B per row)
      const int kbyte = (o ^ ((row & 7) << 4)) & 127;  // inverse-swizzled source
      const char* gA = (const char*)(A + (size_t)(m0 + row) * K + k0) + kbyte;
      const char* gB = (const char*)(Bt + (size_t)(n0 + row) * K + k0) + kbyte;
      __builtin_amdgcn_global_load_lds(
          (const __attribute__((address_space(1))) void*)gA,
          (__attribute__((address_space(3))) void*)(smem + (c << 10)), 16, 0, 0);
      __builtin_amdgcn_global_load_lds(
          (const __attribute__((address_space(1))) void*)gB,
          (__attribute__((address_space(3))) void*)(smem + 16384 + (c << 10)), 16, 0, 0);
    }
    __syncthreads();  // compiler drains vmcnt before s_barrier

#pragma unroll
    for (int ks = 0; ks < 2; ++ks) {
      const int lo = (ks << 6) | (laneHi << 4);
      bf16x8 a[4], b[4];
#pragma unroll
      for (int m = 0; m < 4; ++m)
        a[m] = *(const bf16x8*)(ldsA + ((((aRow + (m << 4)) << 7) + lo) ^ rswz));
#pragma unroll
      for (int n = 0; n < 4; ++n)
        b[n] = *(const bf16x8*)(ldsB + ((((bRow + (n << 4)) << 7) + lo) ^ rswz));
#pragma unroll
      for (int m = 0; m < 4; ++m)
#pragma unroll
        for (int n = 0; n < 4; ++n)
          acc[m][n] = __builtin_amdgcn_mfma_f32_16x16x32_bf16(a[m], b[n], acc[m][n], 0, 0, 0);
    }
    __syncthreads();
  }

  // epilogue: D[r][c], c = lane&15 (col), r = (lane>>4)*4 + reg
#pragma unroll
  for (int n = 0; n < 4; ++n) {
    const int col = n0 + (wc << 6) + (n << 4) + lane15;
    const float bs = bias[col];
#pragma unroll
    for (int m = 0; m < 4; ++m) {
      const int rbase = m0 + (wr << 6) + (m << 4) + (laneHi << 2);
#pragma unroll
      for (int j = 0; j < 4; ++j) {
        const float v = acc[m][n][j] + bs;
        if (GELU) {
          ((unsigned short*)Cout)[(size_t)(rbase + j) * N + col] = f2bf(gelu_tanh(v));
        } else {
          ((float*)Cout)[(size_t)(rbase + j) * N + col] = v;
        }
      }
    }
  }
}

extern "C" void kernel_launch(void* const* d_in, const int* in_sizes, int n_in,
                              void* d_out, int out_size, void* d_ws, size_t ws_size,
                              hipStream_t stream) {
  const float* x     = (const float*)d_in[0];
  const float* gamma = (const float*)d_in[1];
  const float* beta  = (const float*)d_in[2];
  const float* w1    = (const float*)d_in[3];
  const float* b1    = (const float*)d_in[4];
  const float* w2    = (const float*)d_in[5];
  const float* b2    = (const float*)d_in[6];

  unsigned short* lnout = (unsigned short*)d_ws;                                   // 32 MB
  unsigned short* gout  = (unsigned short*)((char*)d_ws + (size_t)32  * 1024 * 1024); // 128 MB
  unsigned short* wT    = (unsigned short*)((char*)d_ws + (size_t)160 * 1024 * 1024); // 128 MB (w1T then w2T)

  ln_kernel<<<TOKENS, 256, 0, stream>>>(x, gamma, beta, lnout);

  transpose_bf16<<<dim3(FC1N / 32, DMODEL / 32), 256, 0, stream>>>(w1, wT, DMODEL, FC1N);
  gemm_bt<true><<<dim3((TOKENS / 128) * (FC1N / 128)), 256, 0, stream>>>(
      lnout, wT, b1, (void*)gout, TOKENS, FC1N, DMODEL);

  transpose_bf16<<<dim3(FC2N / 32, FC1N / 32), 256, 0, stream>>>(w2, wT, FC1N, FC2N);
  gemm_bt<false><<<dim3((TOKENS / 128) * (FC2N / 128)), 256, 0, stream>>>(
      gout, wT, b2, d_out, TOKENS, FC2N, FC1N);
}

// Round 2
// 1206.611 us; speedup vs baseline: 1.4364x; 1.4364x over previous
//
#include <hip/hip_runtime.h>
#include <stdint.h>

#define TOKENS 4096
#define DMODEL 4096
#define FC1N   16384
#define FC2N   4096

typedef __attribute__((ext_vector_type(8))) __bf16 bf16x8;
typedef __attribute__((ext_vector_type(4))) float f32x4;

__device__ __forceinline__ unsigned short f2bf(float f) {
  unsigned u = __float_as_uint(f);
  u += 0x7fffu + ((u >> 16) & 1u);          // RNE
  return (unsigned short)(u >> 16);
}

__device__ __forceinline__ float gelu_tanh(float x) {
  float y = 0.7978845608028654f * (x + 0.044715f * x * x * x);
  float e = __expf(2.0f * y);               // tanh(y) = 1 - 2/(e^(2y)+1)
  float t = 1.0f - 2.0f / (e + 1.0f);
  return 0.5f * x * (1.0f + t);
}

// ---------------- LayerNorm: fp32 [T][D] -> bf16 [T][D] -----------------
__global__ __launch_bounds__(256) void ln_kernel(const float* __restrict__ x,
                                                 const float* __restrict__ gamma,
                                                 const float* __restrict__ beta,
                                                 unsigned short* __restrict__ out) {
  const int row = blockIdx.x;
  const int tid = threadIdx.x;
  const float* xr = x + (size_t)row * DMODEL;
  float4 v[4];
  float s = 0.f, s2 = 0.f;
#pragma unroll
  for (int i = 0; i < 4; ++i) {
    v[i] = ((const float4*)xr)[tid + i * 256];
    s  += v[i].x + v[i].y + v[i].z + v[i].w;
    s2 += v[i].x * v[i].x + v[i].y * v[i].y + v[i].z * v[i].z + v[i].w * v[i].w;
  }
#pragma unroll
  for (int o = 32; o > 0; o >>= 1) {
    s  += __shfl_xor(s, o, 64);
    s2 += __shfl_xor(s2, o, 64);
  }
  __shared__ float red[2][4];
  const int wid = tid >> 6, lane = tid & 63;
  if (lane == 0) { red[0][wid] = s; red[1][wid] = s2; }
  __syncthreads();
  s  = red[0][0] + red[0][1] + red[0][2] + red[0][3];
  s2 = red[1][0] + red[1][1] + red[1][2] + red[1][3];
  const float mu = s * (1.f / DMODEL);
  const float var = s2 * (1.f / DMODEL) - mu * mu;
  const float rs = rsqrtf(var + 1e-3f);
  unsigned short* orow = out + (size_t)row * DMODEL;
#pragma unroll
  for (int i = 0; i < 4; ++i) {
    const int c4 = tid + i * 256;
    float4 g = ((const float4*)gamma)[c4];
    float4 b = ((const float4*)beta)[c4];
    ushort4 o;
    o.x = f2bf((v[i].x - mu) * rs * g.x + b.x);
    o.y = f2bf((v[i].y - mu) * rs * g.y + b.y);
    o.z = f2bf((v[i].z - mu) * rs * g.z + b.z);
    o.w = f2bf((v[i].w - mu) * rs * g.w + b.w);
    ((ushort4*)orow)[c4] = o;
  }
}

// --------- transpose+convert: W fp32 [K][N] -> Wt bf16 [N][K] -----------
__global__ __launch_bounds__(256) void transpose_bf16(const float* __restrict__ W,
                                                      unsigned short* __restrict__ Wt,
                                                      int K, int N) {
  __shared__ float t[32][33];
  const int x = threadIdx.x & 31, y = threadIdx.x >> 5;
  const int n0 = blockIdx.x << 5, k0 = blockIdx.y << 5;
#pragma unroll
  for (int i = 0; i < 4; ++i)
    t[y + i * 8][x] = W[(size_t)(k0 + y + i * 8) * N + n0 + x];
  __syncthreads();
#pragma unroll
  for (int i = 0; i < 4; ++i)
    Wt[(size_t)(n0 + y + i * 8) * K + k0 + x] = f2bf(t[x][y + i * 8]);
}

// ============ 256x256 tile, BK=64, 8-wave, counted-vmcnt GEMM ============
// C = A[M][K](bf16) * Bt[N][K](bf16)^T (+bias, opt GELU)
// LDS per buffer: A[256][64] bf16 @0 (32KB, halves at 0/16K),
//                 B[256][64] bf16 @32768 (halves at 32K/48K). 2 buffers=128KB.
// Swizzle: byte-in-row ^= (row&7)<<4 (write: pre-swizzled global source;
// read: same XOR). Validated round 1 (bank conflicts = 0).

// stage one 128-row x 64-k half-tile: 512 threads x 2 x 16B = 16KB
__device__ __forceinline__ void stage_half(const unsigned short* __restrict__ src,
                                           int K, char* lds) {
  const int tid = threadIdx.x;
#pragma unroll
  for (int r = 0; r < 2; ++r) {
    const int o = ((r << 9) | tid) << 4;              // 0..16383, 16B units
    const int row = o >> 7;                           // 0..127
    const int kb = (o & 127) ^ ((row & 7) << 4);      // inverse-swizzled source col
    const char* g = (const char*)(src + (size_t)row * K) + kb;
    __builtin_amdgcn_global_load_lds(
        (const __attribute__((address_space(1))) void*)g,
        (__attribute__((address_space(3))) void*)(lds + o), 16, 0, 0);
  }
}

__device__ __forceinline__ bf16x8 ldfrag(const char* tile, int row, int koff) {
  return *(const bf16x8*)(tile + row * 128 + (koff ^ ((row & 7) << 4)));
}

template <bool GELU>
__global__ __launch_bounds__(512, 2) void gemm256(const unsigned short* __restrict__ A,
                                                  const unsigned short* __restrict__ Bt,
                                                  const float* __restrict__ bias,
                                                  void* __restrict__ Cout,
                                                  int M, int N, int K) {
  extern __shared__ char smem[];
  const int tid = threadIdx.x;
  const int lane = tid & 63, wid = tid >> 6;
  const int lane15 = lane & 15, laneHi = lane >> 4;

  // XCD-bijective swizzle (nwg % 8 == 0: 1024 and 256)
  const int nwg = gridDim.x;
  const int bid = blockIdx.x;
  const int cpx = nwg >> 3;
  const int wg = (bid & 7) * cpx + (bid >> 3);
  const int nbx = N >> 8;
  const int bx = wg % nbx, by = wg / nbx;
  const int m0 = by << 8, n0 = bx << 8;
  const int wr = wid >> 2, wc = wid & 3;              // 2M x 4N waves
  const int aRow0 = (wr << 7) + lane15;               // + m*16, tile-local A row
  const int bRow0 = (wc << 6) + lane15;               // + n*16, tile-local B row
  const int koffBase = laneHi << 4;

  const int NT = K >> 6;

  f32x4 acc[8][4];
#pragma unroll
  for (int m = 0; m < 8; ++m)
#pragma unroll
    for (int n = 0; n < 4; ++n) acc[m][n] = f32x4{0.f, 0.f, 0.f, 0.f};

  char* cur = smem;
  char* nxt = smem + 65536;

  // ---- prologue: T0 full (8 loads) + T1 lo-halves (4 loads) ----
  stage_half(A  + (size_t)m0 * K,          K, cur);
  stage_half(Bt + (size_t)n0 * K,          K, cur + 32768);
  stage_half(A  + (size_t)(m0 + 128) * K,  K, cur + 16384);
  stage_half(Bt + (size_t)(n0 + 128) * K,  K, cur + 49152);
  stage_half(A  + (size_t)m0 * K + 64,     K, nxt);
  stage_half(Bt + (size_t)n0 * K + 64,     K, nxt + 32768);
  asm volatile("s_waitcnt vmcnt(4)" ::: "memory");    // T0 landed; T1-lo may fly
  __builtin_amdgcn_sched_barrier(0);
  __builtin_amdgcn_s_barrier();
  __builtin_amdgcn_sched_barrier(0);

  bf16x8 a[4][2], b0[2][2], b1[2][2];

  for (int t = 0; t < NT; ++t) {
    const char* Ab = cur;
    const char* Bb = cur + 32768;
    const int k1 = (t + 1) << 6, k2 = (t + 2) << 6;

    // ---------- P0: read A-lo quads + B-lo pair; stage T+1 hi-halves ----------
#pragma unroll
    for (int m = 0; m < 4; ++m)
#pragma unroll
      for (int ks = 0; ks < 2; ++ks)
        a[m][ks] = ldfrag(Ab, aRow0 + m * 16, (ks << 6) | koffBase);
#pragma unroll
    for (int n = 0; n < 2; ++n)
#pragma unroll
      for (int ks = 0; ks < 2; ++ks)
        b0[n][ks] = ldfrag(Bb, bRow0 + n * 16, (ks << 6) | koffBase);
    if (t + 1 < NT) {
      stage_half(A  + (size_t)(m0 + 128) * K + k1, K, nxt + 16384);
      stage_half(Bt + (size_t)(n0 + 128) * K + k1, K, nxt + 49152);
    }
    __builtin_amdgcn_s_barrier();
    __builtin_amdgcn_s_setprio(1);
#pragma unroll
    for (int m = 0; m < 4; ++m)
#pragma unroll
      for (int n = 0; n < 2; ++n)
#pragma unroll
        for (int ks = 0; ks < 2; ++ks)
          acc[m][n] = __builtin_amdgcn_mfma_f32_16x16x32_bf16(a[m][ks], b0[n][ks], acc[m][n], 0, 0, 0);
    __builtin_amdgcn_s_setprio(0);
    __builtin_amdgcn_s_barrier();
    __builtin_amdgcn_sched_barrier(0);

    // ---------- P1: read B-hi pair ----------
#pragma unroll
    for (int n = 0; n < 2; ++n)
#pragma unroll
      for (int ks = 0; ks < 2; ++ks)
        b1[n][ks] = ldfrag(Bb, bRow0 + (n + 2) * 16, (ks << 6) | koffBase);
    __builtin_amdgcn_s_barrier();
    __builtin_amdgcn_s_setprio(1);
#pragma unroll
    for (int m = 0; m < 4; ++m)
#pragma unroll
      for (int n = 0; n < 2; ++n)
#pragma unroll
        for (int ks = 0; ks < 2; ++ks)
          acc[m][n + 2] = __builtin_amdgcn_mfma_f32_16x16x32_bf16(a[m][ks], b1[n][ks], acc[m][n + 2], 0, 0, 0);
    __builtin_amdgcn_s_setprio(0);
    __builtin_amdgcn_s_barrier();
    __builtin_amdgcn_sched_barrier(0);

    // ---------- P2: read A-hi quads ----------
#pragma unroll
    for (int m = 0; m < 4; ++m)
#pragma unroll
      for (int ks = 0; ks < 2; ++ks)
        a[m][ks] = ldfrag(Ab, aRow0 + (m + 4) * 16, (ks << 6) | koffBase);
    __builtin_amdgcn_s_barrier();
    __builtin_amdgcn_s_setprio(1);
#pragma unroll
    for (int m = 0; m < 4; ++m)
#pragma unroll
      for (int n = 0; n < 2; ++n)
#pragma unroll
        for (int ks = 0; ks < 2; ++ks)
          acc[m + 4][n + 2] = __builtin_amdgcn_mfma_f32_16x16x32_bf16(a[m][ks], b1[n][ks], acc[m + 4][n + 2], 0, 0, 0);
    __builtin_amdgcn_s_setprio(0);
    __builtin_amdgcn_s_barrier();
    __builtin_amdgcn_sched_barrier(0);

    // ---------- P3: stage T+2 lo-halves into cur (cur reads done at P2); counted vmcnt ----------
    if (t + 2 < NT) {
      stage_half(A  + (size_t)m0 * K + k2, K, cur);
      stage_half(Bt + (size_t)n0 * K + k2, K, cur + 32768);
      asm volatile("s_waitcnt vmcnt(4)" ::: "memory");  // T+1 fully landed; T+2-lo may fly
    } else {
      asm volatile("s_waitcnt vmcnt(0)" ::: "memory");  // tail: drain T+1
    }
    __builtin_amdgcn_sched_barrier(0);
    __builtin_amdgcn_s_barrier();
    __builtin_amdgcn_s_setprio(1);
#pragma unroll
    for (int m = 0; m < 4; ++m)
#pragma unroll
      for (int n = 0; n < 2; ++n)
#pragma unroll
        for (int ks = 0; ks < 2; ++ks)
          acc[m + 4][n] = __builtin_amdgcn_mfma_f32_16x16x32_bf16(a[m][ks], b0[n][ks], acc[m + 4][n], 0, 0, 0);
    __builtin_amdgcn_s_setprio(0);
    __builtin_amdgcn_s_barrier();
    __builtin_amdgcn_sched_barrier(0);

    char* tmp = cur; cur = nxt; nxt = tmp;
  }

  // ---------------- epilogue: bias (+GELU) and store ----------------
#pragma unroll
  for (int nf = 0; nf < 4; ++nf) {
    const int col = n0 + (wc << 6) + (nf << 4) + lane15;
    const float bs = bias[col];
#pragma unroll
    for (int mf = 0; mf < 8; ++mf) {
      const int rbase = m0 + (wr << 7) + (mf << 4) + (laneHi << 2);
#pragma unroll
      for (int j = 0; j < 4; ++j) {
        const float v = acc[mf][nf][j] + bs;
        if (GELU) {
          ((unsigned short*)Cout)[(size_t)(rbase + j) * N + col] = f2bf(gelu_tanh(v));
        } else {
          ((float*)Cout)[(size_t)(rbase + j) * N + col] = v;
        }
      }
    }
  }
}

extern "C" void kernel_launch(void* const* d_in, const int* in_sizes, int n_in,
                              void* d_out, int out_size, void* d_ws, size_t ws_size,
                              hipStream_t stream) {
  const float* x     = (const float*)d_in[0];
  const float* gamma = (const float*)d_in[1];
  const float* beta  = (const float*)d_in[2];
  const float* w1    = (const float*)d_in[3];
  const float* b1    = (const float*)d_in[4];
  const float* w2    = (const float*)d_in[5];
  const float* b2    = (const float*)d_in[6];

  unsigned short* lnout = (unsigned short*)d_ws;                                      // 32 MB
  unsigned short* gout  = (unsigned short*)((char*)d_ws + (size_t)32  * 1024 * 1024); // 128 MB
  unsigned short* wT    = (unsigned short*)((char*)d_ws + (size_t)160 * 1024 * 1024); // 128 MB

  (void)hipFuncSetAttribute((const void*)gemm256<true>,
                            hipFuncAttributeMaxDynamicSharedMemorySize, 131072);
  (void)hipFuncSetAttribute((const void*)gemm256<false>,
                            hipFuncAttributeMaxDynamicSharedMemorySize, 131072);

  ln_kernel<<<TOKENS, 256, 0, stream>>>(x, gamma, beta, lnout);

  transpose_bf16<<<dim3(FC1N / 32, DMODEL / 32), 256, 0, stream>>>(w1, wT, DMODEL, FC1N);
  gemm256<true><<<dim3((TOKENS / 256) * (FC1N / 256)), 512, 131072, stream>>>(
      lnout, wT, b1, (void*)gout, TOKENS, FC1N, DMODEL);

  transpose_bf16<<<dim3(FC2N / 32, FC1N / 32), 256, 0, stream>>>(w2, wT, FC1N, FC2N);
  gemm256<false><<<dim3((TOKENS / 256) * (FC2N / 256)), 512, 131072, stream>>>(
      gout, wT, b2, d_out, TOKENS, FC2N, FC1N);
}